// Round 13
// baseline (886.454 us; speedup 1.0000x reference)
//
#include <hip/hip_runtime.h>
#include <stdint.h>

#define HW 262144          // 512*512
#define LDIM 33

typedef __bf16 bf16x8 __attribute__((ext_vector_type(8)));
typedef __bf16 bf16x2 __attribute__((ext_vector_type(2)));
typedef float  f32x4  __attribute__((ext_vector_type(4)));

union BF8 { bf16x8 v; unsigned u[4]; };

// native f32->bf16 (RNE) — compiler fuses pairs into v_cvt_pk_bf16_f32
__device__ __forceinline__ unsigned pk2(float a, float b) {
  bf16x2 p; p[0] = (__bf16)a; p[1] = (__bf16)b;
  return __builtin_bit_cast(unsigned, p);
}
__device__ __forceinline__ float exp2_hw(float x) {
  return __builtin_amdgcn_exp2f(x);
}
__device__ __forceinline__ float tanh_fast(float x) {
  float t = exp2_hw(x * 2.8853900818f);
  return 1.0f - __fdividef(2.0f, t + 1.0f);
}
__device__ __forceinline__ float gelu_t(float x) {
  float x2 = x * x;
  float p2 = x * fmaf(0.1029425216f, x2, 2.3021667f);
  float r  = __fdividef(1.0f, exp2_hw(p2) + 1.0f);
  return fmaf(-x, r, x);                                    // x(1 - r)
}

// ====================== KERNEL A: h1 = gelu(W1 ctx + b1) ======================
// 256 thr / 4 waves, 16 px per wave-iter. LDS = W1 only (32 KB).
// Live set ~110 (a1 16 + acc 32 + b1l 32 + addr) -> 4 waves/SIMD at the free
// (256,2) budget; LDS allows 5 blocks/CU -> occupancy 16 waves/CU: this is the
// occupancy the 512MB ctx stream needed (fused kernel was stuck at 2 waves/SIMD).
// h1[px][feat] bf16, 256B/px rows: swapped mfma(W,x) -> lane holds 4 consecutive
// feats at px=n -> one 8B store per ntile.
__global__ __launch_bounds__(256, 2) void gemm1_h1_kernel(
    const float* __restrict__ ctx, const float* __restrict__ W1,
    const float* __restrict__ b1,  char* __restrict__ h1)
{
  __shared__ uint4 smem4[2048];
  char* sm = (char*)smem4;
  const int t    = threadIdx.x;
  const int lane = t & 63;
  const int wv   = t >> 6;        // wave 0..3
  const int n    = lane & 15;
  const int q    = lane >> 4;     // quad 0..3

  // ---- stage W1 (128x128) to LDS as swizzled bf16 ----
  #pragma unroll
  for (int rep = 0; rep < 16; ++rep) {
    int f4 = t + 256 * rep;                 // float4 index 0..4095
    float4 v = ((const float4*)W1)[f4];
    int fi = f4 << 2;
    int o = fi >> 7, k = fi & 127;
    char* dst = sm + o * 256 + (((k >> 3) ^ (o & 15)) << 4) + ((k & 7) << 1);
    *(uint2*)dst = make_uint2(pk2(v.x, v.y), pk2(v.z, v.w));
  }
  __syncthreads();

  // biases per (nt, r): feat = nt*16 + q*4 + r
  float b1l[8][4];
  #pragma unroll
  for (int i = 0; i < 8; ++i)
    #pragma unroll
    for (int r = 0; r < 4; ++r) b1l[i][r] = b1[i * 16 + (q << 2) + r];

  const int p0   = blockIdx.x * 512;        // 512 px per block (never crosses batch)
  const int bi   = p0 >> 18;
  const int sblk = p0 & (HW - 1);
  const float* ctxB = ctx + (size_t)bi * ((size_t)128 * HW);

  #pragma unroll 1
  for (int it = 0; it < 8; ++it) {
    const int sw = sblk + it * 64 + wv * 16;   // wave's 16-px base (in-batch)
    const int gp = p0 + it * 64 + wv * 16 + n; // global px for h1 row

    // ---- A1 fragments: ctx, 4 ksteps ----
    BF8 a1[4];
    {
      const int sA = sw + n;
      #pragma unroll
      for (int ks = 0; ks < 4; ++ks) {
        const float* cb = ctxB + (size_t)(ks * 32 + q * 8) * HW + sA;
        float v0 = cb[0];
        float v1 = cb[(size_t)1 * HW];
        float v2 = cb[(size_t)2 * HW];
        float v3 = cb[(size_t)3 * HW];
        float v4 = cb[(size_t)4 * HW];
        float v5 = cb[(size_t)5 * HW];
        float v6 = cb[(size_t)6 * HW];
        float v7 = cb[(size_t)7 * HW];
        a1[ks].u[0] = pk2(v0, v1);
        a1[ks].u[1] = pk2(v2, v3);
        a1[ks].u[2] = pk2(v4, v5);
        a1[ks].u[3] = pk2(v6, v7);
      }
    }

    // ---- GEMM1 (swapped): D[feat = q*4+r][px = n], all 8 ntiles ----
    f32x4 acc[8];
    #pragma unroll
    for (int j = 0; j < 8; ++j) { f32x4 z = {0.f,0.f,0.f,0.f}; acc[j] = z; }
    #pragma unroll
    for (int ks = 0; ks < 4; ++ks) {
      #pragma unroll
      for (int nt = 0; nt < 8; ++nt) {
        int row = nt * 16 + n;
        bf16x8 bw = *(const bf16x8*)(sm + row * 256 + ((((ks << 2) + q) ^ n) << 4));
        acc[nt] = __builtin_amdgcn_mfma_f32_16x16x32_bf16(bw, a1[ks].v, acc[nt], 0, 0, 0);
      }
    }

    // ---- bias + gelu -> packed bf16 8B stores: h1[gp][nt*16 + q*4 .. +3] ----
    char* hrow = h1 + (size_t)gp * 256;
    #pragma unroll
    for (int nt = 0; nt < 8; ++nt) {
      float g0 = gelu_t(acc[nt][0] + b1l[nt][0]);
      float g1 = gelu_t(acc[nt][1] + b1l[nt][1]);
      float g2 = gelu_t(acc[nt][2] + b1l[nt][2]);
      float g3 = gelu_t(acc[nt][3] + b1l[nt][3]);
      *(uint2*)(hrow + nt * 32 + (q << 3)) = make_uint2(pk2(g0, g1), pk2(g2, g3));
    }
  }
}

// ====== KERNEL B: out = trilinear(lut, img)*2-1 + tanh(W3 gelu(W2 h1+b2)+b3)*osc ======
// 256 thr / 4 waves, 16 px per wave-iter. LDS = W2 (16 KB) + 4x2KB h2 = 24 KB.
// h1 A-fragments read COALESCED from global (16B/lane) — no pack, no transpose.
// Live ~95 regs -> ~5 waves/SIMD; LDS allows 6 blocks/CU.
__global__ __launch_bounds__(256, 2) void mlp_tail_kernel(
    const float* __restrict__ img, const float* __restrict__ lut,
    const char* __restrict__ h1,   const float* __restrict__ W2,
    const float* __restrict__ b2,  const float* __restrict__ W3,
    const float* __restrict__ b3,  const float* __restrict__ oscp,
    float* __restrict__ out)
{
  __shared__ uint4 smem4[1536];
  char* sm = (char*)smem4;
  const int t    = threadIdx.x;
  const int lane = t & 63;
  const int wv   = t >> 6;
  const int n    = lane & 15;
  const int q    = lane >> 4;

  // ---- stage W2 (64x128) to LDS as swizzled bf16 ----
  #pragma unroll
  for (int rep = 0; rep < 8; ++rep) {
    int f4 = t + 256 * rep;                 // 0..2047
    float4 v = ((const float4*)W2)[f4];
    int fi = f4 << 2;
    int o = fi >> 7, k = fi & 127;
    char* dst = sm + o * 256 + (((k >> 3) ^ (o & 15)) << 4) + ((k & 7) << 1);
    *(uint2*)dst = make_uint2(pk2(v.x, v.y), pk2(v.z, v.w));
  }
  __syncthreads();

  float b2l[4][4];
  #pragma unroll
  for (int i = 0; i < 4; ++i)
    #pragma unroll
    for (int r = 0; r < 4; ++r) b2l[i][r] = b2[i * 16 + (q << 2) + r];
  // W3 padded 16x64 as permanent A-fragment pair (rows 3..15 zero)
  BF8 w3a[2];
  #pragma unroll
  for (int ks3 = 0; ks3 < 2; ++ks3) {
    #pragma unroll
    for (int m = 0; m < 4; ++m) {
      float e0 = 0.f, e1 = 0.f;
      if (n < 3) {
        e0 = W3[n * 64 + ks3 * 32 + q * 8 + 2 * m];
        e1 = W3[n * 64 + ks3 * 32 + q * 8 + 2 * m + 1];
      }
      w3a[ks3].u[m] = pk2(e0, e1);
    }
  }
  const float b3a0 = b3[0], b3a1 = b3[1], b3a2 = b3[2];
  const float osc  = oscp[0];

  const int p0   = blockIdx.x * 512;
  const int bi   = p0 >> 18;
  const int sblk = p0 & (HW - 1);
  const float* imgB = img + (size_t)bi * ((size_t)3 * HW);
  float*       outB = out + (size_t)bi * ((size_t)3 * HW);
  char* hb = sm + 16384 + wv * 2048;
  char* hrow = hb + n * 128;
  const int nsw = n & 7;
  const int woff = (q & 1) << 3;

  #pragma unroll 1
  for (int it = 0; it < 8; ++it) {
    const int sw = sblk + it * 64 + wv * 16;
    const int gp = p0 + it * 64 + wv * 16 + n;   // global px for h1 row

    // ---- h1 A-fragments: coalesced 16B loads (issued first, consumed by GEMM2) ----
    bf16x8 a2[4];
    {
      const char* hr = h1 + (size_t)gp * 256;
      #pragma unroll
      for (int ks = 0; ks < 4; ++ks)
        a2[ks] = *(const bf16x8*)(hr + ks * 64 + (q << 4));
    }

    // img + EARLY LUT gathers (L2 latency hides under GEMM2/3)
    const int spf = sw + n;
    const float rr = imgB[spf];
    const float gg = imgB[HW + spf];
    const float bb = imgB[2 * HW + spf];
    float fx, fy, fz;
    float c000, c001, c010, c011, c100, c101, c110, c111;
    {
      float gx = fminf(fmaxf(fmaf(rr, 16.f, 16.f), 0.f), 32.f);  // R -> x (b axis)
      float gy = fminf(fmaxf(fmaf(gg, 16.f, 16.f), 0.f), 32.f);  // G -> y (g axis)
      float gz = fminf(fmaxf(fmaf(bb, 16.f, 16.f), 0.f), 32.f);  // B -> z (r axis)
      int x0 = (int)gx, y0 = (int)gy, z0 = (int)gz;
      fx = gx - (float)x0; fy = gy - (float)y0; fz = gz - (float)z0;
      int x1 = min(x0 + 1, 32), y1 = min(y0 + 1, 32), z1 = min(z0 + 1, 32);
      int zy00 = (z0 * LDIM + y0) * LDIM, zy01 = (z0 * LDIM + y1) * LDIM;
      int zy10 = (z1 * LDIM + y0) * LDIM, zy11 = (z1 * LDIM + y1) * LDIM;
      const int chq = (q < 3) ? q : 2;
      const float* L = lut;
      c000 = L[(zy00 + x0) * 3 + chq]; c001 = L[(zy00 + x1) * 3 + chq];
      c010 = L[(zy01 + x0) * 3 + chq]; c011 = L[(zy01 + x1) * 3 + chq];
      c100 = L[(zy10 + x0) * 3 + chq]; c101 = L[(zy10 + x1) * 3 + chq];
      c110 = L[(zy11 + x0) * 3 + chq]; c111 = L[(zy11 + x1) * 3 + chq];
    }

    // ---- GEMM2 (swapped): D[feat2 = q*4+r][px = n], K=128 in 4 steps ----
    f32x4 acc2[4];
    #pragma unroll
    for (int j = 0; j < 4; ++j) { f32x4 z = {0.f,0.f,0.f,0.f}; acc2[j] = z; }
    #pragma unroll
    for (int ks = 0; ks < 4; ++ks) {
      #pragma unroll
      for (int nt2 = 0; nt2 < 4; ++nt2) {
        int row = nt2 * 16 + n;
        bf16x8 bw = *(const bf16x8*)(sm + row * 256 + ((((ks << 2) + q) ^ n) << 4));
        acc2[nt2] = __builtin_amdgcn_mfma_f32_16x16x32_bf16(bw, a2[ks], acc2[nt2], 0, 0, 0);
      }
    }

    // ---- h2: bias+gelu, packed b64 -> LDS ----
    #pragma unroll
    for (int nt2 = 0; nt2 < 4; ++nt2) {
      float g0 = gelu_t(acc2[nt2][0] + b2l[nt2][0]);
      float g1 = gelu_t(acc2[nt2][1] + b2l[nt2][1]);
      float g2 = gelu_t(acc2[nt2][2] + b2l[nt2][2]);
      float g3 = gelu_t(acc2[nt2][3] + b2l[nt2][3]);
      int kg = (nt2 << 1) + (q >> 1);
      char* dst = hrow + ((kg ^ nsw) << 4) + woff;
      *(uint2*)dst = make_uint2(pk2(g0, g1), pk2(g2, g3));
    }

    // ---- GEMM3: D[ch][px] = W3pad x h2 ----
    f32x4 acc3 = {0.f, 0.f, 0.f, 0.f};
    #pragma unroll
    for (int ks3 = 0; ks3 < 2; ++ks3) {
      bf16x8 hf = *(const bf16x8*)(hrow + ((((ks3 << 2) + q) ^ nsw) << 4));
      acc3 = __builtin_amdgcn_mfma_f32_16x16x32_bf16(w3a[ks3].v, hf, acc3, 0, 0, 0);
    }
    const int ba = n << 2;
    float d0 = __int_as_float(__builtin_amdgcn_ds_bpermute(ba, __float_as_int(acc3[0])));
    float d1 = __int_as_float(__builtin_amdgcn_ds_bpermute(ba, __float_as_int(acc3[1])));
    float d2 = __int_as_float(__builtin_amdgcn_ds_bpermute(ba, __float_as_int(acc3[2])));

    // ---- tail: 48 lanes, ch = q (q<3), px = n ----
    if (q < 3) {
      float sel  = (q == 0) ? d0   : ((q == 1) ? d1   : d2);
      float bsel = (q == 0) ? b3a0 : ((q == 1) ? b3a1 : b3a2);
      float ov = tanh_fast(sel + bsel) * osc;
      float c00 = c000 + fx * (c001 - c000);
      float c01 = c010 + fx * (c011 - c010);
      float c10 = c100 + fx * (c101 - c100);
      float c11 = c110 + fx * (c111 - c110);
      float ca  = c00 + fy * (c01 - c00);
      float cb2 = c10 + fy * (c11 - c10);
      float so  = ca + fz * (cb2 - ca);
      outB[q * HW + sw + n] = so * 2.f - 1.f + ov;
    }
  }
}

// ==================== FALLBACK: r12 monolithic (ws too small) ====================
__global__ __launch_bounds__(256, 2) void local3dlut_fused(
    const float* __restrict__ img,  const float* __restrict__ ctx,
    const float* __restrict__ lut,  const float* __restrict__ W1,
    const float* __restrict__ b1,   const float* __restrict__ W2,
    const float* __restrict__ b2,   const float* __restrict__ W3,
    const float* __restrict__ b3,   const float* __restrict__ oscp,
    float* __restrict__ out)
{
  __shared__ uint4 smem4[3584];
  char* sm = (char*)smem4;
  const int t    = threadIdx.x;
  const int lane = t & 63;
  const int wv   = t >> 6;
  const int n    = lane & 15;
  const int q    = lane >> 4;

  #pragma unroll
  for (int rep = 0; rep < 16; ++rep) {
    int f4 = t + 256 * rep;
    float4 v = ((const float4*)W1)[f4];
    int fi = f4 << 2;
    int o = fi >> 7, k = fi & 127;
    char* dst = sm + o * 256 + (((k >> 3) ^ (o & 15)) << 4) + ((k & 7) << 1);
    *(uint2*)dst = make_uint2(pk2(v.x, v.y), pk2(v.z, v.w));
  }
  #pragma unroll
  for (int rep = 0; rep < 8; ++rep) {
    int f4 = t + 256 * rep;
    float4 v = ((const float4*)W2)[f4];
    int fi = f4 << 2;
    int o = fi >> 7, k = fi & 127;
    char* dst = sm + 32768 + o * 256 + (((k >> 3) ^ (o & 15)) << 4) + ((k & 7) << 1);
    *(uint2*)dst = make_uint2(pk2(v.x, v.y), pk2(v.z, v.w));
  }
  __syncthreads();

  float b1l[8][4];
  #pragma unroll
  for (int i = 0; i < 8; ++i)
    #pragma unroll
    for (int r = 0; r < 4; ++r) b1l[i][r] = b1[i * 16 + (q << 2) + r];
  float b2l[4][4];
  #pragma unroll
  for (int i = 0; i < 4; ++i)
    #pragma unroll
    for (int r = 0; r < 4; ++r) b2l[i][r] = b2[i * 16 + (q << 2) + r];
  BF8 w3a[2];
  #pragma unroll
  for (int ks3 = 0; ks3 < 2; ++ks3) {
    #pragma unroll
    for (int m = 0; m < 4; ++m) {
      float e0 = 0.f, e1 = 0.f;
      if (n < 3) {
        e0 = W3[n * 64 + ks3 * 32 + q * 8 + 2 * m];
        e1 = W3[n * 64 + ks3 * 32 + q * 8 + 2 * m + 1];
      }
      w3a[ks3].u[m] = pk2(e0, e1);
    }
  }
  const float b3a0 = b3[0], b3a1 = b3[1], b3a2 = b3[2];
  const float osc  = oscp[0];

  const int p0   = blockIdx.x * 512;
  const int bi   = p0 >> 18;
  const int sblk = p0 & (HW - 1);
  const float* ctxB = ctx + (size_t)bi * ((size_t)128 * HW);
  const float* imgB = img + (size_t)bi * ((size_t)3 * HW);
  float*       outB = out + (size_t)bi * ((size_t)3 * HW);
  char* hb = sm + 49152 + wv * 2048;
  char* hrow = hb + n * 128;
  const int nsw = n & 7;
  const int woff = (q & 1) << 3;

  #pragma unroll 1
  for (int it = 0; it < 8; ++it) {
    const int sw = sblk + it * 64 + wv * 16;
    const int spf = sw + n;
    const float rr = imgB[spf];
    const float gg = imgB[HW + spf];
    const float bb = imgB[2 * HW + spf];

    BF8 a1[4];
    {
      const int sA = sw + n;
      #pragma unroll
      for (int ks = 0; ks < 4; ++ks) {
        const float* cb = ctxB + (size_t)(ks * 32 + q * 8) * HW + sA;
        float v0 = cb[0];
        float v1 = cb[(size_t)1 * HW];
        float v2 = cb[(size_t)2 * HW];
        float v3 = cb[(size_t)3 * HW];
        float v4 = cb[(size_t)4 * HW];
        float v5 = cb[(size_t)5 * HW];
        float v6 = cb[(size_t)6 * HW];
        float v7 = cb[(size_t)7 * HW];
        a1[ks].u[0] = pk2(v0, v1);
        a1[ks].u[1] = pk2(v2, v3);
        a1[ks].u[2] = pk2(v4, v5);
        a1[ks].u[3] = pk2(v6, v7);
      }
    }

    float fx, fy, fz;
    float c000, c001, c010, c011, c100, c101, c110, c111;
    {
      float gx = fminf(fmaxf(fmaf(rr, 16.f, 16.f), 0.f), 32.f);
      float gy = fminf(fmaxf(fmaf(gg, 16.f, 16.f), 0.f), 32.f);
      float gz = fminf(fmaxf(fmaf(bb, 16.f, 16.f), 0.f), 32.f);
      int x0 = (int)gx, y0 = (int)gy, z0 = (int)gz;
      fx = gx - (float)x0; fy = gy - (float)y0; fz = gz - (float)z0;
      int x1 = min(x0 + 1, 32), y1 = min(y0 + 1, 32), z1 = min(z0 + 1, 32);
      int zy00 = (z0 * LDIM + y0) * LDIM, zy01 = (z0 * LDIM + y1) * LDIM;
      int zy10 = (z1 * LDIM + y0) * LDIM, zy11 = (z1 * LDIM + y1) * LDIM;
      const int chq = (q < 3) ? q : 2;
      const float* L = lut;
      c000 = L[(zy00 + x0) * 3 + chq]; c001 = L[(zy00 + x1) * 3 + chq];
      c010 = L[(zy01 + x0) * 3 + chq]; c011 = L[(zy01 + x1) * 3 + chq];
      c100 = L[(zy10 + x0) * 3 + chq]; c101 = L[(zy10 + x1) * 3 + chq];
      c110 = L[(zy11 + x0) * 3 + chq]; c111 = L[(zy11 + x1) * 3 + chq];
    }

    f32x4 acc2[4];
    #pragma unroll
    for (int j = 0; j < 4; ++j) { f32x4 z = {0.f,0.f,0.f,0.f}; acc2[j] = z; }

    #pragma unroll
    for (int half = 0; half < 2; ++half) {
      f32x4 acc1[4];
      #pragma unroll
      for (int j = 0; j < 4; ++j) { f32x4 z = {0.f,0.f,0.f,0.f}; acc1[j] = z; }
      #pragma unroll
      for (int ks = 0; ks < 4; ++ks) {
        #pragma unroll
        for (int nt4 = 0; nt4 < 4; ++nt4) {
          int row = (half * 4 + nt4) * 16 + n;
          bf16x8 bw = *(const bf16x8*)(sm + row * 256 + ((((ks << 2) + q) ^ n) << 4));
          acc1[nt4] = __builtin_amdgcn_mfma_f32_16x16x32_bf16(bw, a1[ks].v, acc1[nt4], 0, 0, 0);
        }
      }
      #pragma unroll
      for (int nt4 = 0; nt4 < 4; ++nt4) {
        float g0 = gelu_t(acc1[nt4][0] + b1l[half * 4 + nt4][0]);
        float g1 = gelu_t(acc1[nt4][1] + b1l[half * 4 + nt4][1]);
        float g2 = gelu_t(acc1[nt4][2] + b1l[half * 4 + nt4][2]);
        float g3 = gelu_t(acc1[nt4][3] + b1l[half * 4 + nt4][3]);
        int kg = (nt4 << 1) + (q >> 1);
        char* dst = hrow + ((kg ^ nsw) << 4) + woff;
        *(uint2*)dst = make_uint2(pk2(g0, g1), pk2(g2, g3));
      }
      #pragma unroll
      for (int ks2 = 0; ks2 < 2; ++ks2) {
        bf16x8 a2 = *(const bf16x8*)(hrow + ((((ks2 << 2) + q) ^ nsw) << 4));
        #pragma unroll
        for (int nt2 = 0; nt2 < 4; ++nt2) {
          int row = nt2 * 16 + n;
          int kg2 = half * 8 + (ks2 << 2) + q;
          bf16x8 bw = *(const bf16x8*)(sm + 32768 + row * 256 + ((kg2 ^ n) << 4));
          acc2[nt2] = __builtin_amdgcn_mfma_f32_16x16x32_bf16(bw, a2, acc2[nt2], 0, 0, 0);
        }
      }
    }

    #pragma unroll
    for (int nt2 = 0; nt2 < 4; ++nt2) {
      float g0 = gelu_t(acc2[nt2][0] + b2l[nt2][0]);
      float g1 = gelu_t(acc2[nt2][1] + b2l[nt2][1]);
      float g2 = gelu_t(acc2[nt2][2] + b2l[nt2][2]);
      float g3 = gelu_t(acc2[nt2][3] + b2l[nt2][3]);
      int kg = (nt2 << 1) + (q >> 1);
      char* dst = hrow + ((kg ^ nsw) << 4) + woff;
      *(uint2*)dst = make_uint2(pk2(g0, g1), pk2(g2, g3));
    }

    f32x4 acc3 = {0.f, 0.f, 0.f, 0.f};
    #pragma unroll
    for (int ks3 = 0; ks3 < 2; ++ks3) {
      bf16x8 hf = *(const bf16x8*)(hrow + ((((ks3 << 2) + q) ^ nsw) << 4));
      acc3 = __builtin_amdgcn_mfma_f32_16x16x32_bf16(w3a[ks3].v, hf, acc3, 0, 0, 0);
    }
    const int ba = n << 2;
    float d0 = __int_as_float(__builtin_amdgcn_ds_bpermute(ba, __float_as_int(acc3[0])));
    float d1 = __int_as_float(__builtin_amdgcn_ds_bpermute(ba, __float_as_int(acc3[1])));
    float d2 = __int_as_float(__builtin_amdgcn_ds_bpermute(ba, __float_as_int(acc3[2])));

    if (q < 3) {
      float sel  = (q == 0) ? d0   : ((q == 1) ? d1   : d2);
      float bsel = (q == 0) ? b3a0 : ((q == 1) ? b3a1 : b3a2);
      float ov = tanh_fast(sel + bsel) * osc;
      float c00 = c000 + fx * (c001 - c000);
      float c01 = c010 + fx * (c011 - c010);
      float c10 = c100 + fx * (c101 - c100);
      float c11 = c110 + fx * (c111 - c110);
      float ca  = c00 + fy * (c01 - c00);
      float cb2 = c10 + fy * (c11 - c10);
      float so  = ca + fz * (cb2 - ca);
      outB[q * HW + sw + n] = so * 2.f - 1.f + ov;
    }
  }
}

extern "C" void kernel_launch(void* const* d_in, const int* in_sizes, int n_in,
                              void* d_out, int out_size, void* d_ws, size_t ws_size,
                              hipStream_t stream) {
  const float* img = (const float*)d_in[0];
  const float* ctx = (const float*)d_in[1];
  const float* lut = (const float*)d_in[2];
  const float* W1  = (const float*)d_in[3];
  const float* b1  = (const float*)d_in[4];
  const float* W2  = (const float*)d_in[5];
  const float* b2  = (const float*)d_in[6];
  const float* W3  = (const float*)d_in[7];
  const float* b3  = (const float*)d_in[8];
  const float* osc = (const float*)d_in[9];
  float* out = (float*)d_out;
  const size_t h1_bytes = (size_t)4 * HW * 256;   // 1Mpx x 128 feat x bf16 = 256 MiB
  if (ws_size >= h1_bytes && d_ws != nullptr) {
    // Pass A: h1 = gelu(W1 ctx + b1) at 16 waves/CU (LDS 32KB, ~110 regs)
    gemm1_h1_kernel<<<dim3(2048), dim3(256), 0, stream>>>(ctx, W1, b1, (char*)d_ws);
    // Pass B: GEMM2/3 + LUT + combine (h1 read coalesced; LDS 24KB, ~95 regs)
    mlp_tail_kernel<<<dim3(2048), dim3(256), 0, stream>>>(
        img, lut, (const char*)d_ws, W2, b2, W3, b3, osc, out);
  } else {
    // fallback: r12 monolithic
    local3dlut_fused<<<dim3(2048), dim3(256), 0, stream>>>(
        img, ctx, lut, W1, b1, W2, b2, W3, b3, osc, out);
  }
}

// Round 14
// 780.480 us; speedup vs baseline: 1.1358x; 1.1358x over previous
//
#include <hip/hip_runtime.h>
#include <stdint.h>

#define HW 262144          // 512*512
#define LDIM 33

typedef __bf16 bf16x8 __attribute__((ext_vector_type(8)));
typedef __bf16 bf16x2 __attribute__((ext_vector_type(2)));
typedef float  f32x4  __attribute__((ext_vector_type(4)));

union BF8 { bf16x8 v; unsigned u[4]; };

// native f32->bf16 (RNE) — compiler fuses pairs into v_cvt_pk_bf16_f32
__device__ __forceinline__ unsigned pk2(float a, float b) {
  bf16x2 p; p[0] = (__bf16)a; p[1] = (__bf16)b;
  return __builtin_bit_cast(unsigned, p);
}
__device__ __forceinline__ float exp2_hw(float x) {
  return __builtin_amdgcn_exp2f(x);
}
__device__ __forceinline__ float tanh_fast(float x) {
  float t = exp2_hw(x * 2.8853900818f);
  return 1.0f - __fdividef(2.0f, t + 1.0f);
}
__device__ __forceinline__ float gelu_t(float x) {
  float x2 = x * x;
  float p2 = x * fmaf(0.1029425216f, x2, 2.3021667f);
  float r  = __fdividef(1.0f, exp2_hw(p2) + 1.0f);
  return fmaf(-x, r, x);                                    // x(1 - r)
}

// issue the 32 raw ctx loads for one 16-px wave tile (fragment order)
__device__ __forceinline__ void load_raw16(float (&raw)[4][8],
    const float* __restrict__ ctxB, int swb, int n, int q) {
  #pragma unroll
  for (int ks = 0; ks < 4; ++ks) {
    const float* cb = ctxB + (size_t)(ks * 32 + q * 8) * HW + swb + n;
    #pragma unroll
    for (int j = 0; j < 8; ++j)
      raw[ks][j] = cb[(size_t)j * HW];
  }
}

// LDS map (57344 B, 256 threads / 4 waves — free-budget no-spill chassis):
//   [0,     32768)  W1 bf16: 128 rows x 256B, 16B group kg stored at (kg ^ (row&15))
//   [32768, 49152)  W2 bf16:  64 rows x 256B, same swizzle
//   [49152, 57344)  per-wave h: 4 waves x 2048B (16 px rows x 128B, swizz kg^(px&7))
//
// r14 = r12 chassis (swapped GEMMs, packed-b64 transpose, GEMM3 tail, early-LUT)
// + CROSS-ITERATION ctx PREFETCH with a PINNED issue point:
//   pack(raw_i) -> load raw_{i+1} -> sched_barrier(0) -> compute_i
// The sched_barrier(0) stops the scheduler from sinking the prefetch to its use
// (r11's silent failure mode under register pressure). Loads then stay in flight
// across the full GEMM1..GEMM3 span (~2500cy) instead of draining before compute
// (loads-outstanding duty cycle ~25% -> ~860 GB/s observed; this lifts it).
// Live set ~165 + raw(32) ~= 197 -> free (256,2) budget, no spill.
__global__ __launch_bounds__(256, 2) void local3dlut_kernel(
    const float* __restrict__ img,  const float* __restrict__ ctx,
    const float* __restrict__ lut,  const float* __restrict__ W1,
    const float* __restrict__ b1,   const float* __restrict__ W2,
    const float* __restrict__ b2,   const float* __restrict__ W3,
    const float* __restrict__ b3,   const float* __restrict__ oscp,
    float* __restrict__ out)
{
  __shared__ uint4 smem4[3584];
  char* sm = (char*)smem4;
  const int t    = threadIdx.x;
  const int lane = t & 63;
  const int wv   = t >> 6;        // wave 0..3
  const int n    = lane & 15;
  const int q    = lane >> 4;     // quad 0..3

  // ---- stage W1 (128x128) and W2 (64x128) to LDS as swizzled bf16 ----
  #pragma unroll
  for (int rep = 0; rep < 16; ++rep) {
    int f4 = t + 256 * rep;                 // float4 index 0..4095
    float4 v = ((const float4*)W1)[f4];
    int fi = f4 << 2;
    int o = fi >> 7, k = fi & 127;
    char* dst = sm + o * 256 + (((k >> 3) ^ (o & 15)) << 4) + ((k & 7) << 1);
    *(uint2*)dst = make_uint2(pk2(v.x, v.y), pk2(v.z, v.w));
  }
  #pragma unroll
  for (int rep = 0; rep < 8; ++rep) {
    int f4 = t + 256 * rep;                 // 0..2047
    float4 v = ((const float4*)W2)[f4];
    int fi = f4 << 2;
    int o = fi >> 7, k = fi & 127;
    char* dst = sm + 32768 + o * 256 + (((k >> 3) ^ (o & 15)) << 4) + ((k & 7) << 1);
    *(uint2*)dst = make_uint2(pk2(v.x, v.y), pk2(v.z, v.w));
  }
  __syncthreads();

  // per-lane constants (swapped layout: biases indexed by feat = blk*16 + q*4 + r)
  float b1l[8][4];
  #pragma unroll
  for (int i = 0; i < 8; ++i)
    #pragma unroll
    for (int r = 0; r < 4; ++r) b1l[i][r] = b1[i * 16 + (q << 2) + r];
  float b2l[4][4];
  #pragma unroll
  for (int i = 0; i < 4; ++i)
    #pragma unroll
    for (int r = 0; r < 4; ++r) b2l[i][r] = b2[i * 16 + (q << 2) + r];
  // W3 padded 16x64 as a permanent A-fragment pair (rows 3..15 zero)
  BF8 w3a[2];
  #pragma unroll
  for (int ks3 = 0; ks3 < 2; ++ks3) {
    #pragma unroll
    for (int m = 0; m < 4; ++m) {
      float e0 = 0.f, e1 = 0.f;
      if (n < 3) {
        e0 = W3[n * 64 + ks3 * 32 + q * 8 + 2 * m];
        e1 = W3[n * 64 + ks3 * 32 + q * 8 + 2 * m + 1];
      }
      w3a[ks3].u[m] = pk2(e0, e1);
    }
  }
  const float b3a0 = b3[0], b3a1 = b3[1], b3a2 = b3[2];
  const float osc  = oscp[0];

  const int p0   = blockIdx.x * 512;        // 512 px per block, never crosses batch b
  const int bi   = p0 >> 18;
  const int sblk = p0 & (HW - 1);
  const float* ctxB = ctx + (size_t)bi * ((size_t)128 * HW);
  const float* imgB = img + (size_t)bi * ((size_t)3 * HW);
  float*       outB = out + (size_t)bi * ((size_t)3 * HW);
  char* hb = sm + 49152 + wv * 2048;
  char* hrow = hb + n * 128;
  const int nsw = n & 7;
  const int woff = (q & 1) << 3;            // 8B half within the 16B group

  // ---- prologue: issue iteration 0's ctx loads ----
  float raw[4][8];
  load_raw16(raw, ctxB, sblk + wv * 16, n, q);

  #pragma unroll 1
  for (int it = 0; it < 8; ++it) {
    const int sw = sblk + it * 64 + wv * 16;   // wave's 16-px base in image

    // ---- pack raw (iter it) into A1 fragments ----
    BF8 a1[4];
    #pragma unroll
    for (int ks = 0; ks < 4; ++ks) {
      a1[ks].u[0] = pk2(raw[ks][0], raw[ks][1]);
      a1[ks].u[1] = pk2(raw[ks][2], raw[ks][3]);
      a1[ks].u[2] = pk2(raw[ks][4], raw[ks][5]);
      a1[ks].u[3] = pk2(raw[ks][6], raw[ks][7]);
    }

    // ---- PREFETCH next iteration's ctx (branchless clamp), then PIN the
    //      issue point so the scheduler cannot sink these loads into the
    //      compute phase (r11's silent failure). ----
    {
      int itn = (it < 7) ? it + 1 : 7;
      load_raw16(raw, ctxB, sblk + itn * 64 + wv * 16, n, q);
    }
    __builtin_amdgcn_sched_barrier(0);

    // img loads for this lane's tail pixel (px = n)
    const int spf = sw + n;
    const float rr = imgB[spf];
    const float gg = imgB[HW + spf];
    const float bb = imgB[2 * HW + spf];

    // ---- EARLY LUT: indices + all 8 corner gathers (L2 latency hides under
    //      GEMM1..GEMM3). All lanes gather (ch clamped for q==3). ----
    float fx, fy, fz;
    float c000, c001, c010, c011, c100, c101, c110, c111;
    {
      float gx = fminf(fmaxf(fmaf(rr, 16.f, 16.f), 0.f), 32.f);  // R -> x (b axis)
      float gy = fminf(fmaxf(fmaf(gg, 16.f, 16.f), 0.f), 32.f);  // G -> y (g axis)
      float gz = fminf(fmaxf(fmaf(bb, 16.f, 16.f), 0.f), 32.f);  // B -> z (r axis)
      int x0 = (int)gx, y0 = (int)gy, z0 = (int)gz;
      fx = gx - (float)x0; fy = gy - (float)y0; fz = gz - (float)z0;
      int x1 = min(x0 + 1, 32), y1 = min(y0 + 1, 32), z1 = min(z0 + 1, 32);
      int zy00 = (z0 * LDIM + y0) * LDIM, zy01 = (z0 * LDIM + y1) * LDIM;
      int zy10 = (z1 * LDIM + y0) * LDIM, zy11 = (z1 * LDIM + y1) * LDIM;
      const int chq = (q < 3) ? q : 2;
      const float* L = lut;
      c000 = L[(zy00 + x0) * 3 + chq]; c001 = L[(zy00 + x1) * 3 + chq];
      c010 = L[(zy01 + x0) * 3 + chq]; c011 = L[(zy01 + x1) * 3 + chq];
      c100 = L[(zy10 + x0) * 3 + chq]; c101 = L[(zy10 + x1) * 3 + chq];
      c110 = L[(zy11 + x0) * 3 + chq]; c111 = L[(zy11 + x1) * 3 + chq];
    }

    f32x4 acc2[4];
    #pragma unroll
    for (int j = 0; j < 4; ++j) { f32x4 z = {0.f,0.f,0.f,0.f}; acc2[j] = z; }

    #pragma unroll
    for (int half = 0; half < 2; ++half) {
      // ---- GEMM1 (SWAPPED): D[feat = q*4+r][px = n] ----
      f32x4 acc1[4];
      #pragma unroll
      for (int j = 0; j < 4; ++j) { f32x4 z = {0.f,0.f,0.f,0.f}; acc1[j] = z; }

      #pragma unroll
      for (int ks = 0; ks < 4; ++ks) {
        #pragma unroll
        for (int nt4 = 0; nt4 < 4; ++nt4) {
          int row = (half * 4 + nt4) * 16 + n;
          bf16x8 bw = *(const bf16x8*)(sm + row * 256 + ((((ks << 2) + q) ^ n) << 4));
          acc1[nt4] = __builtin_amdgcn_mfma_f32_16x16x32_bf16(bw, a1[ks].v, acc1[nt4], 0, 0, 0);
        }
      }
      // ---- h1: bias+gelu, pack 4 consecutive feats -> ONE ds_write_b64 per nt4 ----
      #pragma unroll
      for (int nt4 = 0; nt4 < 4; ++nt4) {
        float g0 = gelu_t(acc1[nt4][0] + b1l[half * 4 + nt4][0]);
        float g1 = gelu_t(acc1[nt4][1] + b1l[half * 4 + nt4][1]);
        float g2 = gelu_t(acc1[nt4][2] + b1l[half * 4 + nt4][2]);
        float g3 = gelu_t(acc1[nt4][3] + b1l[half * 4 + nt4][3]);
        int kg = (nt4 << 1) + (q >> 1);       // 16B feature group within 128B row
        char* dst = hrow + ((kg ^ nsw) << 4) + woff;
        *(uint2*)dst = make_uint2(pk2(g0, g1), pk2(g2, g3));
      }
      // ---- GEMM2 (SWAPPED) partial: D[feat2 = q*4+r][px = n] ----
      #pragma unroll
      for (int ks2 = 0; ks2 < 2; ++ks2) {
        bf16x8 a2 = *(const bf16x8*)(hrow + ((((ks2 << 2) + q) ^ nsw) << 4));
        #pragma unroll
        for (int nt2 = 0; nt2 < 4; ++nt2) {
          int row = nt2 * 16 + n;
          int kg2 = half * 8 + (ks2 << 2) + q;
          bf16x8 bw = *(const bf16x8*)(sm + 32768 + row * 256 + ((kg2 ^ n) << 4));
          acc2[nt2] = __builtin_amdgcn_mfma_f32_16x16x32_bf16(bw, a2, acc2[nt2], 0, 0, 0);
        }
      }
    }

    // ---- h2: bias+gelu, packed b64 writes (4 total) ----
    #pragma unroll
    for (int nt2 = 0; nt2 < 4; ++nt2) {
      float g0 = gelu_t(acc2[nt2][0] + b2l[nt2][0]);
      float g1 = gelu_t(acc2[nt2][1] + b2l[nt2][1]);
      float g2 = gelu_t(acc2[nt2][2] + b2l[nt2][2]);
      float g3 = gelu_t(acc2[nt2][3] + b2l[nt2][3]);
      int kg = (nt2 << 1) + (q >> 1);
      char* dst = hrow + ((kg ^ nsw) << 4) + woff;
      *(uint2*)dst = make_uint2(pk2(g0, g1), pk2(g2, g3));
    }

    // ---- GEMM3: D[ch][px] = W3pad(16x64) x h2 ----
    f32x4 acc3 = {0.f, 0.f, 0.f, 0.f};
    #pragma unroll
    for (int ks3 = 0; ks3 < 2; ++ks3) {
      bf16x8 hf = *(const bf16x8*)(hrow + ((((ks3 << 2) + q) ^ nsw) << 4));
      acc3 = __builtin_amdgcn_mfma_f32_16x16x32_bf16(w3a[ks3].v, hf, acc3, 0, 0, 0);
    }
    // q=0 rows r=0..2 hold ch 0..2 for px=n -> redistribute to lane (n, q<3)
    const int ba = n << 2;
    float d0 = __int_as_float(__builtin_amdgcn_ds_bpermute(ba, __float_as_int(acc3[0])));
    float d1 = __int_as_float(__builtin_amdgcn_ds_bpermute(ba, __float_as_int(acc3[1])));
    float d2 = __int_as_float(__builtin_amdgcn_ds_bpermute(ba, __float_as_int(acc3[2])));

    // ---- tail: 48 lanes, ch = q (q<3), px = n; corners + offset in-register ----
    if (q < 3) {
      float sel  = (q == 0) ? d0   : ((q == 1) ? d1   : d2);
      float bsel = (q == 0) ? b3a0 : ((q == 1) ? b3a1 : b3a2);
      float ov = tanh_fast(sel + bsel) * osc;

      float c00 = c000 + fx * (c001 - c000);
      float c01 = c010 + fx * (c011 - c010);
      float c10 = c100 + fx * (c101 - c100);
      float c11 = c110 + fx * (c111 - c110);
      float ca  = c00 + fy * (c01 - c00);
      float cb2 = c10 + fy * (c11 - c10);
      float so  = ca + fz * (cb2 - ca);
      outB[q * HW + sw + n] = so * 2.f - 1.f + ov;
    }
  }
}

extern "C" void kernel_launch(void* const* d_in, const int* in_sizes, int n_in,
                              void* d_out, int out_size, void* d_ws, size_t ws_size,
                              hipStream_t stream) {
  const float* img = (const float*)d_in[0];
  const float* ctx = (const float*)d_in[1];
  const float* lut = (const float*)d_in[2];
  const float* W1  = (const float*)d_in[3];
  const float* b1  = (const float*)d_in[4];
  const float* W2  = (const float*)d_in[5];
  const float* b2  = (const float*)d_in[6];
  const float* W3  = (const float*)d_in[7];
  const float* b3  = (const float*)d_in[8];
  const float* osc = (const float*)d_in[9];
  float* out = (float*)d_out;
  // 2048 blocks x 512 px; 256 threads (4 waves), 56 KB LDS -> 2 blocks/CU,
  // free 256-reg budget (no spill), cross-iter pinned ctx prefetch
  local3dlut_kernel<<<dim3(2048), dim3(256), 0, stream>>>(
      img, ctx, lut, W1, b1, W2, b2, W3, b3, osc, out);
}